// Round 1
// baseline (754.749 us; speedup 1.0000x reference)
//
#include <hip/hip_runtime.h>
#include <hip/hip_bf16.h>

// NeLDA forward: loglik[b] = sum_v cnt_v * bnlin[b,v] - T * log(sum_v exp(bnlin[b,v]))
// bnlin[b,v] = g_v * (thetac_b . W_v) * rsqrt(var_v + eps) + bb_v   (all BN biases cancel)

using bf16x8 = __attribute__((ext_vector_type(8))) __bf16;
using f32x4  = __attribute__((ext_vector_type(4))) float;

#define MROWS 1024
#define VDIM  50000
#define HDIM  100
#define HP    112
#define KDIM  200
#define KP    224
#define TTOK  32768
#define KPAD1 50432
#define NCH   32
#define CHLEN 1600
#define EBLK  782   // ceil(50000/64)

__device__ __forceinline__ f32x4 mfma16(bf16x8 a, bf16x8 b, f32x4 c) {
  return __builtin_amdgcn_mfma_f32_16x16x32_bf16(a, b, c, 0, 0, 0);
}
__device__ __forceinline__ float softplus_f(float x) {
  return x > 20.f ? x : log1pf(__expf(x));
}

// ---------------- token histogram ----------------
__global__ void k_zero(float* __restrict__ cnt) {
  int id = blockIdx.x * 256 + threadIdx.x;
  if (id < VDIM) cnt[id] = 0.f;
}
__global__ void k_hist(const int* __restrict__ tok, float* __restrict__ cnt) {
  int id = blockIdx.x * 256 + threadIdx.x;
  if (id < TTOK) atomicAdd(&cnt[tok[id]], 1.f);
}

// ---------------- fc1_w [50000][100] -> bf16 col-major [112][50432] (zero padded) ----------------
__global__ __launch_bounds__(256) void k_fc1t(const float* __restrict__ w, __bf16* __restrict__ out) {
  __shared__ float tile[32][33];
  int kt = blockIdx.x, ct = blockIdx.y;
  int t = threadIdx.x;
  #pragma unroll
  for (int i = 0; i < 4; ++i) {
    int idx = t + i * 256;
    int lr = idx >> 5, lc = idx & 31;
    int gk = kt * 32 + lr, gc = ct * 32 + lc;
    tile[lr][lc] = (gk < VDIM && gc < HDIM) ? w[(size_t)gk * HDIM + gc] : 0.f;
  }
  __syncthreads();
  #pragma unroll
  for (int i = 0; i < 4; ++i) {
    int idx = t + i * 256;
    int lc = idx >> 5, lr = idx & 31;
    int gc = ct * 32 + lc, gk = kt * 32 + lr;
    if (gc < HP) out[(size_t)gc * KPAD1 + gk] = (__bf16)tile[lr][lc];
  }
}

// ---------------- GEMM1 split-K: partial[ch][row][112] = bows-chunk @ fc1 ----------------
__global__ __launch_bounds__(256, 4) void k_gemm1(const float* __restrict__ bows,
    const __bf16* __restrict__ fc1T, float* __restrict__ partial) {
  const int wave = threadIdx.x >> 6, lane = threadIdx.x & 63;
  const int lrow = lane & 15, lgrp = lane >> 4;
  const int rowbase = blockIdx.x * 64 + wave * 16;
  const int row = rowbase + lrow;
  const int ch = blockIdx.y;
  const int k0 = ch * CHLEN;
  const int kend = min(k0 + CHLEN, VDIM);
  const int nsteps = (kend - k0 + 31) >> 5;
  f32x4 acc[7] = {};
  const float* ap = bows + (size_t)row * VDIM;
  for (int s = 0; s < nsteps; ++s) {
    const int kl = k0 + s * 32 + lgrp * 8;
    bf16x8 a;
    if (kl + 8 <= VDIM) {
      f32x4 x0 = *(const f32x4*)(ap + kl);
      f32x4 x1 = *(const f32x4*)(ap + kl + 4);
      #pragma unroll
      for (int j = 0; j < 4; ++j) { a[j] = (__bf16)x0[j]; a[j + 4] = (__bf16)x1[j]; }
    } else {
      #pragma unroll
      for (int j = 0; j < 8; ++j) a[j] = (__bf16)((kl + j < VDIM) ? ap[kl + j] : 0.f);
    }
    #pragma unroll
    for (int n = 0; n < 7; ++n) {
      bf16x8 b = *(const bf16x8*)(fc1T + (size_t)(n * 16 + lrow) * KPAD1 + kl);
      acc[n] = mfma16(a, b, acc[n]);
    }
  }
  float* pp = partial + (size_t)ch * MROWS * HP;
  #pragma unroll
  for (int n = 0; n < 7; ++n) {
    #pragma unroll
    for (int r = 0; r < 4; ++r) {
      int rr = rowbase + lgrp * 4 + r;
      pp[(size_t)rr * HP + n * 16 + lrow] = acc[n][r];
    }
  }
}

// ---------------- reduce split-K + bias + softplus -> h1 [1024][100] ----------------
__global__ void k_h1(const float* __restrict__ partial, const float* __restrict__ fc1_b,
                     float* __restrict__ h1) {
  int id = blockIdx.x * 256 + threadIdx.x;
  if (id >= MROWS * HDIM) return;
  int row = id / HDIM, h = id % HDIM;
  float s = fc1_b[h];
  #pragma unroll 4
  for (int c = 0; c < NCH; ++c) s += partial[((size_t)c * MROWS + row) * HP + h];
  h1[id] = softplus_f(s);
}

// ---------------- fused: h2 = softplus(h1@fc2+b2); mu_lin/sig_lin (bias-free, cancels in BN) ----------------
__global__ __launch_bounds__(256) void k_mlp(const float* __restrict__ h1,
    const float* __restrict__ fc2_w, const float* __restrict__ fc2_b,
    const float* __restrict__ mu_w, const float* __restrict__ sig_w,
    float* __restrict__ mu_lin, float* __restrict__ sig_lin) {
  __shared__ float h1r[HDIM], h2r[HDIM];
  int row = blockIdx.x, t = threadIdx.x;
  if (t < HDIM) h1r[t] = h1[(size_t)row * HDIM + t];
  __syncthreads();
  if (t < HDIM) {
    float s = fc2_b[t];
    #pragma unroll 4
    for (int k = 0; k < HDIM; ++k) s += h1r[k] * fc2_w[k * HDIM + t];
    h2r[t] = softplus_f(s);
  }
  __syncthreads();
  if (t < KDIM) {
    float sm = 0.f, ss = 0.f;
    #pragma unroll 4
    for (int k = 0; k < HDIM; ++k) {
      float h = h2r[k];
      sm += h * mu_w[k * KDIM + t];
      ss += h * sig_w[k * KDIM + t];
    }
    mu_lin[(size_t)row * KDIM + t] = sm;
    sig_lin[(size_t)row * KDIM + t] = ss;
  }
}

// ---------------- BN stats for mu/sig: scale/shift per column ----------------
__global__ __launch_bounds__(256) void k_bnstats(const float* __restrict__ mu_lin,
    const float* __restrict__ sig_lin, const float* __restrict__ bn_mu_g,
    const float* __restrict__ bn_mu_b, const float* __restrict__ bn_sig_g,
    const float* __restrict__ bn_sig_b, float* __restrict__ bnsc, float* __restrict__ bnsh) {
  int bid = blockIdx.x;
  int mat = bid / KDIM, col = bid % KDIM;
  const float* src = mat ? sig_lin : mu_lin;
  int t = threadIdx.x;
  float s = 0.f, q = 0.f;
  for (int b = t; b < MROWS; b += 256) {
    float v = src[(size_t)b * KDIM + col];
    s += v; q += v * v;
  }
  #pragma unroll
  for (int d = 1; d < 64; d <<= 1) { s += __shfl_xor(s, d, 64); q += __shfl_xor(q, d, 64); }
  __shared__ float ls[4], lq[4];
  if ((t & 63) == 0) { ls[t >> 6] = s; lq[t >> 6] = q; }
  __syncthreads();
  if (t == 0) {
    s = ls[0] + ls[1] + ls[2] + ls[3];
    q = lq[0] + lq[1] + lq[2] + lq[3];
    float mean = s * (1.f / MROWS);
    float var = q * (1.f / MROWS) - mean * mean;
    float g = mat ? bn_sig_g[col] : bn_mu_g[col];
    float bb = mat ? bn_sig_b[col] : bn_mu_b[col];
    float sc = g * rsqrtf(var + 1e-5f);
    bnsc[mat * KDIM + col] = sc;
    bnsh[mat * KDIM + col] = bb - sc * mean;
  }
}

// ---------------- theta = exp(bn_mu + exp(0.5*bn_sig)*eps) ----------------
__global__ void k_theta(const float* __restrict__ mu_lin, const float* __restrict__ sig_lin,
    const float* __restrict__ eps, const float* __restrict__ bnsc, const float* __restrict__ bnsh,
    float* __restrict__ theta) {
  int id = blockIdx.x * 256 + threadIdx.x;
  if (id >= MROWS * KDIM) return;
  int k = id % KDIM;
  float mz = mu_lin[id] * bnsc[k] + bnsh[k];
  float sz = sig_lin[id] * bnsc[KDIM + k] + bnsh[KDIM + k];
  theta[id] = __expf(mz + __expf(0.5f * sz) * eps[id]);
}

// ---------------- column means of theta ----------------
__global__ __launch_bounds__(256) void k_tbar(const float* __restrict__ theta, float* __restrict__ tbar) {
  int col = blockIdx.x, t = threadIdx.x;
  float s = 0.f;
  for (int b = t; b < MROWS; b += 256) s += theta[(size_t)b * KDIM + col];
  #pragma unroll
  for (int d = 1; d < 64; d <<= 1) s += __shfl_xor(s, d, 64);
  __shared__ float ls[4];
  if ((t & 63) == 0) ls[t >> 6] = s;
  __syncthreads();
  if (t == 0) tbar[col] = (ls[0] + ls[1] + ls[2] + ls[3]) * (1.f / MROWS);
}

// ---------------- centered theta -> bf16 [1024][224] (zero padded K) ----------------
__global__ void k_center(const float* __restrict__ theta, const float* __restrict__ tbar,
                         __bf16* __restrict__ thetac) {
  int id = blockIdx.x * 256 + threadIdx.x;
  if (id >= MROWS * KP) return;
  int b = id / KP, kp = id % KP;
  thetac[id] = (kp < KDIM) ? (__bf16)(theta[(size_t)b * KDIM + kp] - tbar[kp]) : (__bf16)0.f;
}

// ---------------- fused decode: Dw = thetac@W (MFMA), batch var per col, exp-sum + cnt-weighted sum per row ----------------
__global__ __launch_bounds__(512, 4) void k_decode(
    const __bf16* __restrict__ thetac,          // [1024][224]
    const float* __restrict__ beta_w,           // [200][50000]
    const float* __restrict__ bn_g, const float* __restrict__ bn_b,
    const float* __restrict__ cnt,
    float* __restrict__ part_e, float* __restrict__ part_t) {
  __shared__ __bf16 ldsW[32][232];
  __shared__ float red[8][32];
  __shared__ float s_s[32], s_bb[32], s_ct[32];
  const int tid = threadIdx.x;
  const int wave = tid >> 6, lane = tid & 63;
  const int lrow = lane & 15, lgrp = lane >> 4;
  float esum[8] = {0, 0, 0, 0, 0, 0, 0, 0};
  float tsum[8] = {0, 0, 0, 0, 0, 0, 0, 0};
  const int cbase = blockIdx.x * 64;
  const __bf16* tp = thetac + (size_t)(wave * 128 + lrow) * KP + lgrp * 8;

  #pragma unroll 1
  for (int chunk = 0; chunk < 2; ++chunk) {
    const int cb = cbase + chunk * 32;
    if (cb >= VDIM) break;
    // stage W slice: ldsW[c][k] = beta_w[k][cb+c] (bf16, zero pad)
    #pragma unroll
    for (int p = 0; p < 14; ++p) {
      int idx = p * 512 + tid;
      int k = idx >> 5, c = idx & 31;
      float v = (k < KDIM && cb + c < VDIM) ? beta_w[(size_t)k * VDIM + cb + c] : 0.f;
      ldsW[c][k] = (__bf16)v;
    }
    __syncthreads();
    // MFMA: A = W-slice^T (M=32 cols), B = thetac^T (N=128 rows/wave)
    f32x4 acc[2][8];
    #pragma unroll
    for (int mf = 0; mf < 2; ++mf)
      #pragma unroll
      for (int nf = 0; nf < 8; ++nf) acc[mf][nf] = (f32x4){0, 0, 0, 0};
    #pragma unroll
    for (int ks = 0; ks < 7; ++ks) {
      bf16x8 a0 = *(const bf16x8*)&ldsW[lrow][ks * 32 + lgrp * 8];
      bf16x8 a1 = *(const bf16x8*)&ldsW[16 + lrow][ks * 32 + lgrp * 8];
      #pragma unroll
      for (int nf = 0; nf < 8; ++nf) {
        bf16x8 b = *(const bf16x8*)(tp + (size_t)nf * 16 * KP + ks * 32);
        acc[0][nf] = mfma16(a0, b, acc[0][nf]);
        acc[1][nf] = mfma16(a1, b, acc[1][nf]);
      }
    }
    // per-column sum of Dw^2 over all 1024 rows
    float vs[2][4];
    #pragma unroll
    for (int mf = 0; mf < 2; ++mf)
      #pragma unroll
      for (int r = 0; r < 4; ++r) {
        float v = 0.f;
        #pragma unroll
        for (int nf = 0; nf < 8; ++nf) { float d = acc[mf][nf][r]; v += d * d; }
        #pragma unroll
        for (int d = 1; d <= 8; d <<= 1) v += __shfl_xor(v, d, 64);
        vs[mf][r] = v;
      }
    if (lrow == 0) {
      #pragma unroll
      for (int mf = 0; mf < 2; ++mf)
        #pragma unroll
        for (int r = 0; r < 4; ++r)
          red[wave][mf * 16 + lgrp * 4 + r] = vs[mf][r];
    }
    __syncthreads();
    if (tid < 32) {
      float v = 0.f;
      #pragma unroll
      for (int w8 = 0; w8 < 8; ++w8) v += red[w8][tid];
      float var = v * (1.f / 1024.f);
      int col = cb + tid;
      bool valid = col < VDIM;
      float g = valid ? bn_g[col] : 0.f;
      float bb = valid ? bn_b[col] : -87.f;
      float ct = valid ? cnt[col] : 0.f;
      s_s[tid] = g * rsqrtf(var + 1e-5f);
      s_bb[tid] = bb;
      s_ct[tid] = ct;
    }
    __syncthreads();
    // epilogue: bnlin = s*Dw + bb; accumulate exp and cnt*bnlin per row
    #pragma unroll
    for (int mf = 0; mf < 2; ++mf)
      #pragma unroll
      for (int r = 0; r < 4; ++r) {
        int col = mf * 16 + lgrp * 4 + r;
        float s = s_s[col], bb = s_bb[col], ct = s_ct[col];
        #pragma unroll
        for (int nf = 0; nf < 8; ++nf) {
          float z = s * acc[mf][nf][r] + bb;
          esum[nf] += __expf(z);
          tsum[nf] += ct * z;
        }
      }
    __syncthreads();
  }
  // reduce over the 4 lane-groups (cols) and write per-row partials
  #pragma unroll
  for (int nf = 0; nf < 8; ++nf) {
    float e = esum[nf], t = tsum[nf];
    e += __shfl_xor(e, 16, 64); e += __shfl_xor(e, 32, 64);
    t += __shfl_xor(t, 16, 64); t += __shfl_xor(t, 32, 64);
    if (lgrp == 0) {
      int row = wave * 128 + nf * 16 + lrow;
      part_e[(size_t)blockIdx.x * MROWS + row] = e;
      part_t[(size_t)blockIdx.x * MROWS + row] = t;
    }
  }
}

// ---------------- final: loglik[b] = tok[b] - T*log(esum[b]) ----------------
__global__ __launch_bounds__(256) void k_final(const float* __restrict__ part_e,
    const float* __restrict__ part_t, float* __restrict__ out) {
  __shared__ float se[8][32], st[8][32];
  int t = threadIdx.x;
  int rloc = t & 31, g = t >> 5;
  int row = blockIdx.x * 32 + rloc;
  float e = 0.f, s = 0.f;
  for (int blk = g; blk < EBLK; blk += 8) {
    e += part_e[(size_t)blk * MROWS + row];
    s += part_t[(size_t)blk * MROWS + row];
  }
  se[g][rloc] = e; st[g][rloc] = s;
  __syncthreads();
  if (t < 32) {
    float et = 0.f, tt = 0.f;
    #pragma unroll
    for (int i = 0; i < 8; ++i) { et += se[i][t]; tt += st[i][t]; }
    out[blockIdx.x * 32 + t] = tt - 32768.f * logf(et);
  }
}

extern "C" void kernel_launch(void* const* d_in, const int* in_sizes, int n_in,
                              void* d_out, int out_size, void* d_ws, size_t ws_size,
                              hipStream_t stream) {
  (void)in_sizes; (void)n_in; (void)out_size; (void)ws_size;
  const float* bows      = (const float*)d_in[0];
  const float* eps       = (const float*)d_in[1];
  const int*   toks      = (const int*)d_in[2];
  const float* fc1_w     = (const float*)d_in[3];
  const float* fc1_b     = (const float*)d_in[4];
  const float* fc2_w     = (const float*)d_in[5];
  const float* fc2_b     = (const float*)d_in[6];
  const float* mu_w      = (const float*)d_in[7];
  const float* bn_mu_g   = (const float*)d_in[9];
  const float* bn_mu_b   = (const float*)d_in[10];
  const float* sig_w     = (const float*)d_in[11];
  const float* bn_sig_g  = (const float*)d_in[13];
  const float* bn_sig_b  = (const float*)d_in[14];
  const float* beta_w    = (const float*)d_in[15];
  const float* bn_beta_g = (const float*)d_in[17];
  const float* bn_beta_b = (const float*)d_in[18];

  char* w = (char*)d_ws;
  auto alloc = [&](size_t b) { char* p = w; w += (b + 255) & ~(size_t)255; return p; };
  __bf16* fc1T   = (__bf16*)alloc((size_t)HP * KPAD1 * 2);
  float* partial = (float*)alloc((size_t)NCH * MROWS * HP * 4);
  float* h1      = (float*)alloc((size_t)MROWS * HDIM * 4);
  float* mu_lin  = (float*)alloc((size_t)MROWS * KDIM * 4);
  float* sig_lin = (float*)alloc((size_t)MROWS * KDIM * 4);
  float* bnsc    = (float*)alloc(2 * KDIM * 4);
  float* bnsh    = (float*)alloc(2 * KDIM * 4);
  float* theta   = (float*)alloc((size_t)MROWS * KDIM * 4);
  float* tbar    = (float*)alloc(KDIM * 4);
  __bf16* thetac = (__bf16*)alloc((size_t)MROWS * KP * 2);
  float* cnt     = (float*)alloc((size_t)VDIM * 4);
  float* part_e  = (float*)alloc((size_t)EBLK * MROWS * 4);
  float* part_t  = (float*)alloc((size_t)EBLK * MROWS * 4);

  k_zero<<<(VDIM + 255) / 256, 256, 0, stream>>>(cnt);
  k_hist<<<(TTOK + 255) / 256, 256, 0, stream>>>(toks, cnt);
  k_fc1t<<<dim3(KPAD1 / 32, 4), 256, 0, stream>>>(fc1_w, fc1T);
  k_gemm1<<<dim3(16, NCH), 256, 0, stream>>>(bows, fc1T, partial);
  k_h1<<<(MROWS * HDIM + 255) / 256, 256, 0, stream>>>(partial, fc1_b, h1);
  k_mlp<<<MROWS, 256, 0, stream>>>(h1, fc2_w, fc2_b, mu_w, sig_w, mu_lin, sig_lin);
  k_bnstats<<<2 * KDIM, 256, 0, stream>>>(mu_lin, sig_lin, bn_mu_g, bn_mu_b, bn_sig_g, bn_sig_b, bnsc, bnsh);
  k_theta<<<(MROWS * KDIM + 255) / 256, 256, 0, stream>>>(mu_lin, sig_lin, eps, bnsc, bnsh, theta);
  k_tbar<<<KDIM, 256, 0, stream>>>(theta, tbar);
  k_center<<<(MROWS * KP + 255) / 256, 256, 0, stream>>>(theta, tbar, thetac);
  k_decode<<<EBLK, 512, 0, stream>>>(thetac, beta_w, bn_beta_g, bn_beta_b, cnt, part_e, part_t);
  k_final<<<MROWS / 32, 256, 0, stream>>>(part_e, part_t, (float*)d_out);
}

// Round 2
// 731.391 us; speedup vs baseline: 1.0319x; 1.0319x over previous
//
#include <hip/hip_runtime.h>
#include <hip/hip_bf16.h>

// NeLDA forward: loglik[b] = sum_v cnt_v * bnlin[b,v] - T * log(sum_v exp(bnlin[b,v]))
// bnlin[b,v] = g_v * (thetac_b . W_v) * rsqrt(var_v + eps) + bb_v   (all BN biases cancel)

using bf16x8 = __attribute__((ext_vector_type(8))) __bf16;
using f32x4  = __attribute__((ext_vector_type(4))) float;

#define MROWS 1024
#define VDIM  50000
#define HDIM  100
#define HP    112
#define KDIM  200
#define KP    224
#define TTOK  32768
#define KPAD1 50432
#define NCH   64
#define CHLEN 800
#define EBLK  782   // ceil(50000/64)

__device__ __forceinline__ f32x4 mfma16(bf16x8 a, bf16x8 b, f32x4 c) {
  return __builtin_amdgcn_mfma_f32_16x16x32_bf16(a, b, c, 0, 0, 0);
}
__device__ __forceinline__ float softplus_f(float x) {
  return x > 20.f ? x : log1pf(__expf(x));
}

// ---------------- token histogram ----------------
__global__ void k_zero(float* __restrict__ cnt) {
  int id = blockIdx.x * 256 + threadIdx.x;
  if (id < VDIM) cnt[id] = 0.f;
}
__global__ void k_hist(const int* __restrict__ tok, float* __restrict__ cnt) {
  int id = blockIdx.x * 256 + threadIdx.x;
  if (id < TTOK) atomicAdd(&cnt[tok[id]], 1.f);
}

// ---------------- fc1_w [50000][100] -> bf16 col-major [112][50432] (zero padded) ----------------
__global__ __launch_bounds__(256) void k_fc1t(const float* __restrict__ w, __bf16* __restrict__ out) {
  __shared__ float tile[32][33];
  int kt = blockIdx.x, ct = blockIdx.y;
  int t = threadIdx.x;
  #pragma unroll
  for (int i = 0; i < 4; ++i) {
    int idx = t + i * 256;
    int lr = idx >> 5, lc = idx & 31;
    int gk = kt * 32 + lr, gc = ct * 32 + lc;
    tile[lr][lc] = (gk < VDIM && gc < HDIM) ? w[(size_t)gk * HDIM + gc] : 0.f;
  }
  __syncthreads();
  #pragma unroll
  for (int i = 0; i < 4; ++i) {
    int idx = t + i * 256;
    int lc = idx >> 5, lr = idx & 31;
    int gc = ct * 32 + lc, gk = kt * 32 + lr;
    if (gc < HP) out[(size_t)gc * KPAD1 + gk] = (__bf16)tile[lr][lc];
  }
}

// ---------------- GEMM1 split-K: partial[ch][row][112] = bows-chunk @ fc1 ----------------
__global__ __launch_bounds__(256, 4) void k_gemm1(const float* __restrict__ bows,
    const __bf16* __restrict__ fc1T, float* __restrict__ partial) {
  const int wave = threadIdx.x >> 6, lane = threadIdx.x & 63;
  const int lrow = lane & 15, lgrp = lane >> 4;
  const int rowbase = blockIdx.x * 64 + wave * 16;
  const int row = rowbase + lrow;
  const int ch = blockIdx.y;
  const int k0 = ch * CHLEN;
  const int kend = min(k0 + CHLEN, VDIM);
  const int nsteps = (kend - k0 + 31) >> 5;
  f32x4 acc[7] = {};
  const float* ap = bows + (size_t)row * VDIM;
  for (int s = 0; s < nsteps; ++s) {
    const int kl = k0 + s * 32 + lgrp * 8;
    bf16x8 a;
    if (kl + 8 <= VDIM) {
      f32x4 x0 = *(const f32x4*)(ap + kl);
      f32x4 x1 = *(const f32x4*)(ap + kl + 4);
      #pragma unroll
      for (int j = 0; j < 4; ++j) { a[j] = (__bf16)x0[j]; a[j + 4] = (__bf16)x1[j]; }
    } else {
      #pragma unroll
      for (int j = 0; j < 8; ++j) a[j] = (__bf16)((kl + j < VDIM) ? ap[kl + j] : 0.f);
    }
    #pragma unroll
    for (int n = 0; n < 7; ++n) {
      bf16x8 b = *(const bf16x8*)(fc1T + (size_t)(n * 16 + lrow) * KPAD1 + kl);
      acc[n] = mfma16(a, b, acc[n]);
    }
  }
  float* pp = partial + (size_t)ch * MROWS * HP;
  #pragma unroll
  for (int n = 0; n < 7; ++n) {
    #pragma unroll
    for (int r = 0; r < 4; ++r) {
      int rr = rowbase + lgrp * 4 + r;
      pp[(size_t)rr * HP + n * 16 + lrow] = acc[n][r];
    }
  }
}

// ---------------- reduce split-K + bias + softplus -> h1 [1024][100] ----------------
__global__ void k_h1(const float* __restrict__ partial, const float* __restrict__ fc1_b,
                     float* __restrict__ h1) {
  int id = blockIdx.x * 256 + threadIdx.x;
  if (id >= MROWS * HDIM) return;
  int row = id / HDIM, h = id % HDIM;
  float s = fc1_b[h];
  #pragma unroll 4
  for (int c = 0; c < NCH; ++c) s += partial[((size_t)c * MROWS + row) * HP + h];
  h1[id] = softplus_f(s);
}

// ---------------- fused: h2 = softplus(h1@fc2+b2); mu_lin/sig_lin (bias-free, cancels in BN) ----------------
__global__ __launch_bounds__(256) void k_mlp(const float* __restrict__ h1,
    const float* __restrict__ fc2_w, const float* __restrict__ fc2_b,
    const float* __restrict__ mu_w, const float* __restrict__ sig_w,
    float* __restrict__ mu_lin, float* __restrict__ sig_lin) {
  __shared__ float h1r[HDIM], h2r[HDIM];
  int row = blockIdx.x, t = threadIdx.x;
  if (t < HDIM) h1r[t] = h1[(size_t)row * HDIM + t];
  __syncthreads();
  if (t < HDIM) {
    float s = fc2_b[t];
    #pragma unroll 4
    for (int k = 0; k < HDIM; ++k) s += h1r[k] * fc2_w[k * HDIM + t];
    h2r[t] = softplus_f(s);
  }
  __syncthreads();
  if (t < KDIM) {
    float sm = 0.f, ss = 0.f;
    #pragma unroll 4
    for (int k = 0; k < HDIM; ++k) {
      float h = h2r[k];
      sm += h * mu_w[k * KDIM + t];
      ss += h * sig_w[k * KDIM + t];
    }
    mu_lin[(size_t)row * KDIM + t] = sm;
    sig_lin[(size_t)row * KDIM + t] = ss;
  }
}

// ---------------- BN stats for mu/sig: scale/shift per column ----------------
__global__ __launch_bounds__(256) void k_bnstats(const float* __restrict__ mu_lin,
    const float* __restrict__ sig_lin, const float* __restrict__ bn_mu_g,
    const float* __restrict__ bn_mu_b, const float* __restrict__ bn_sig_g,
    const float* __restrict__ bn_sig_b, float* __restrict__ bnsc, float* __restrict__ bnsh) {
  int bid = blockIdx.x;
  int mat = bid / KDIM, col = bid % KDIM;
  const float* src = mat ? sig_lin : mu_lin;
  int t = threadIdx.x;
  float s = 0.f, q = 0.f;
  for (int b = t; b < MROWS; b += 256) {
    float v = src[(size_t)b * KDIM + col];
    s += v; q += v * v;
  }
  #pragma unroll
  for (int d = 1; d < 64; d <<= 1) { s += __shfl_xor(s, d, 64); q += __shfl_xor(q, d, 64); }
  __shared__ float ls[4], lq[4];
  if ((t & 63) == 0) { ls[t >> 6] = s; lq[t >> 6] = q; }
  __syncthreads();
  if (t == 0) {
    s = ls[0] + ls[1] + ls[2] + ls[3];
    q = lq[0] + lq[1] + lq[2] + lq[3];
    float mean = s * (1.f / MROWS);
    float var = q * (1.f / MROWS) - mean * mean;
    float g = mat ? bn_sig_g[col] : bn_mu_g[col];
    float bb = mat ? bn_sig_b[col] : bn_mu_b[col];
    float sc = g * rsqrtf(var + 1e-5f);
    bnsc[mat * KDIM + col] = sc;
    bnsh[mat * KDIM + col] = bb - sc * mean;
  }
}

// ---------------- theta = exp(bn_mu + exp(0.5*bn_sig)*eps) ----------------
__global__ void k_theta(const float* __restrict__ mu_lin, const float* __restrict__ sig_lin,
    const float* __restrict__ eps, const float* __restrict__ bnsc, const float* __restrict__ bnsh,
    float* __restrict__ theta) {
  int id = blockIdx.x * 256 + threadIdx.x;
  if (id >= MROWS * KDIM) return;
  int k = id % KDIM;
  float mz = mu_lin[id] * bnsc[k] + bnsh[k];
  float sz = sig_lin[id] * bnsc[KDIM + k] + bnsh[KDIM + k];
  theta[id] = __expf(mz + __expf(0.5f * sz) * eps[id]);
}

// ---------------- column means of theta ----------------
__global__ __launch_bounds__(256) void k_tbar(const float* __restrict__ theta, float* __restrict__ tbar) {
  int col = blockIdx.x, t = threadIdx.x;
  float s = 0.f;
  for (int b = t; b < MROWS; b += 256) s += theta[(size_t)b * KDIM + col];
  #pragma unroll
  for (int d = 1; d < 64; d <<= 1) s += __shfl_xor(s, d, 64);
  __shared__ float ls[4];
  if ((t & 63) == 0) ls[t >> 6] = s;
  __syncthreads();
  if (t == 0) tbar[col] = (ls[0] + ls[1] + ls[2] + ls[3]) * (1.f / MROWS);
}

// ---------------- centered theta -> bf16 [1024][224] (zero padded K) ----------------
__global__ void k_center(const float* __restrict__ theta, const float* __restrict__ tbar,
                         __bf16* __restrict__ thetac) {
  int id = blockIdx.x * 256 + threadIdx.x;
  if (id >= MROWS * KP) return;
  int b = id / KP, kp = id % KP;
  thetac[id] = (kp < KDIM) ? (__bf16)(theta[(size_t)b * KDIM + kp] - tbar[kp]) : (__bf16)0.f;
}

// ---------------- fused decode: Dw = thetac@W (MFMA), batch var per col, exp-sum + cnt-weighted sum per row ----------------
__global__ __launch_bounds__(512, 2) void k_decode(
    const __bf16* __restrict__ thetac,          // [1024][224]
    const float* __restrict__ beta_w,           // [200][50000]
    const float* __restrict__ bn_g, const float* __restrict__ bn_b,
    const float* __restrict__ cnt,
    float* __restrict__ part_e, float* __restrict__ part_t) {
  __shared__ __bf16 ldsW[32][232];
  __shared__ float red[8][32];
  __shared__ float s_s[32], s_bb[32], s_ct[32];
  const int tid = threadIdx.x;
  const int wave = tid >> 6, lane = tid & 63;
  const int lrow = lane & 15, lgrp = lane >> 4;
  float esum[8] = {0, 0, 0, 0, 0, 0, 0, 0};
  float tsum[8] = {0, 0, 0, 0, 0, 0, 0, 0};
  const int cbase = blockIdx.x * 64;
  const __bf16* tp = thetac + (size_t)(wave * 128 + lrow) * KP + lgrp * 8;

  #pragma unroll 1
  for (int chunk = 0; chunk < 2; ++chunk) {
    const int cb = cbase + chunk * 32;
    if (cb >= VDIM) break;
    // stage W slice: ldsW[c][k] = beta_w[k][cb+c] (bf16, zero pad)
    #pragma unroll
    for (int p = 0; p < 14; ++p) {
      int idx = p * 512 + tid;
      int k = idx >> 5, c = idx & 31;
      float v = (k < KDIM && cb + c < VDIM) ? beta_w[(size_t)k * VDIM + cb + c] : 0.f;
      ldsW[c][k] = (__bf16)v;
    }
    __syncthreads();
    // MFMA: A = W-slice^T (M=32 cols), B = thetac^T (N=128 rows/wave)
    f32x4 acc[2][8];
    #pragma unroll
    for (int mf = 0; mf < 2; ++mf)
      #pragma unroll
      for (int nf = 0; nf < 8; ++nf) acc[mf][nf] = (f32x4){0, 0, 0, 0};
    #pragma unroll
    for (int ks = 0; ks < 7; ++ks) {
      bf16x8 a0 = *(const bf16x8*)&ldsW[lrow][ks * 32 + lgrp * 8];
      bf16x8 a1 = *(const bf16x8*)&ldsW[16 + lrow][ks * 32 + lgrp * 8];
      #pragma unroll
      for (int nf = 0; nf < 8; ++nf) {
        bf16x8 b = *(const bf16x8*)(tp + (size_t)nf * 16 * KP + ks * 32);
        acc[0][nf] = mfma16(a0, b, acc[0][nf]);
        acc[1][nf] = mfma16(a1, b, acc[1][nf]);
      }
    }
    // per-column sum of Dw^2 over all 1024 rows
    float vs[2][4];
    #pragma unroll
    for (int mf = 0; mf < 2; ++mf)
      #pragma unroll
      for (int r = 0; r < 4; ++r) {
        float v = 0.f;
        #pragma unroll
        for (int nf = 0; nf < 8; ++nf) { float d = acc[mf][nf][r]; v += d * d; }
        #pragma unroll
        for (int d = 1; d <= 8; d <<= 1) v += __shfl_xor(v, d, 64);
        vs[mf][r] = v;
      }
    if (lrow == 0) {
      #pragma unroll
      for (int mf = 0; mf < 2; ++mf)
        #pragma unroll
        for (int r = 0; r < 4; ++r)
          red[wave][mf * 16 + lgrp * 4 + r] = vs[mf][r];
    }
    __syncthreads();
    if (tid < 32) {
      float v = 0.f;
      #pragma unroll
      for (int w8 = 0; w8 < 8; ++w8) v += red[w8][tid];
      float var = v * (1.f / 1024.f);
      int col = cb + tid;
      bool valid = col < VDIM;
      float g = valid ? bn_g[col] : 0.f;
      float bb = valid ? bn_b[col] : -87.f;
      float ct = valid ? cnt[col] : 0.f;
      s_s[tid] = g * rsqrtf(var + 1e-5f);
      s_bb[tid] = bb;
      s_ct[tid] = ct;
    }
    __syncthreads();
    // epilogue: bnlin = s*Dw + bb; accumulate exp and cnt*bnlin per row
    #pragma unroll
    for (int mf = 0; mf < 2; ++mf)
      #pragma unroll
      for (int r = 0; r < 4; ++r) {
        int col = mf * 16 + lgrp * 4 + r;
        float s = s_s[col], bb = s_bb[col], ct = s_ct[col];
        #pragma unroll
        for (int nf = 0; nf < 8; ++nf) {
          float z = s * acc[mf][nf][r] + bb;
          esum[nf] += __expf(z);
          tsum[nf] += ct * z;
        }
      }
    __syncthreads();
  }
  // reduce over the 4 lane-groups (cols) and write per-row partials
  #pragma unroll
  for (int nf = 0; nf < 8; ++nf) {
    float e = esum[nf], t = tsum[nf];
    e += __shfl_xor(e, 16, 64); e += __shfl_xor(e, 32, 64);
    t += __shfl_xor(t, 16, 64); t += __shfl_xor(t, 32, 64);
    if (lgrp == 0) {
      int row = wave * 128 + nf * 16 + lrow;
      part_e[(size_t)blockIdx.x * MROWS + row] = e;
      part_t[(size_t)blockIdx.x * MROWS + row] = t;
    }
  }
}

// ---------------- final: loglik[b] = tok[b] - T*log(esum[b]) ----------------
__global__ __launch_bounds__(256) void k_final(const float* __restrict__ part_e,
    const float* __restrict__ part_t, float* __restrict__ out) {
  __shared__ float se[8][32], st[8][32];
  int t = threadIdx.x;
  int rloc = t & 31, g = t >> 5;
  int row = blockIdx.x * 32 + rloc;
  float e = 0.f, s = 0.f;
  for (int blk = g; blk < EBLK; blk += 8) {
    e += part_e[(size_t)blk * MROWS + row];
    s += part_t[(size_t)blk * MROWS + row];
  }
  se[g][rloc] = e; st[g][rloc] = s;
  __syncthreads();
  if (t < 32) {
    float et = 0.f, tt = 0.f;
    #pragma unroll
    for (int i = 0; i < 8; ++i) { et += se[i][t]; tt += st[i][t]; }
    out[blockIdx.x * 32 + t] = tt - 32768.f * logf(et);
  }
}

extern "C" void kernel_launch(void* const* d_in, const int* in_sizes, int n_in,
                              void* d_out, int out_size, void* d_ws, size_t ws_size,
                              hipStream_t stream) {
  (void)in_sizes; (void)n_in; (void)out_size; (void)ws_size;
  const float* bows      = (const float*)d_in[0];
  const float* eps       = (const float*)d_in[1];
  const int*   toks      = (const int*)d_in[2];
  const float* fc1_w     = (const float*)d_in[3];
  const float* fc1_b     = (const float*)d_in[4];
  const float* fc2_w     = (const float*)d_in[5];
  const float* fc2_b     = (const float*)d_in[6];
  const float* mu_w      = (const float*)d_in[7];
  const float* bn_mu_g   = (const float*)d_in[9];
  const float* bn_mu_b   = (const float*)d_in[10];
  const float* sig_w     = (const float*)d_in[11];
  const float* bn_sig_g  = (const float*)d_in[13];
  const float* bn_sig_b  = (const float*)d_in[14];
  const float* beta_w    = (const float*)d_in[15];
  const float* bn_beta_g = (const float*)d_in[17];
  const float* bn_beta_b = (const float*)d_in[18];

  char* w = (char*)d_ws;
  auto alloc = [&](size_t b) { char* p = w; w += (b + 255) & ~(size_t)255; return p; };
  __bf16* fc1T   = (__bf16*)alloc((size_t)HP * KPAD1 * 2);
  float* partial = (float*)alloc((size_t)NCH * MROWS * HP * 4);
  float* h1      = (float*)alloc((size_t)MROWS * HDIM * 4);
  float* mu_lin  = (float*)alloc((size_t)MROWS * KDIM * 4);
  float* sig_lin = (float*)alloc((size_t)MROWS * KDIM * 4);
  float* bnsc    = (float*)alloc(2 * KDIM * 4);
  float* bnsh    = (float*)alloc(2 * KDIM * 4);
  float* theta   = (float*)alloc((size_t)MROWS * KDIM * 4);
  float* tbar    = (float*)alloc(KDIM * 4);
  __bf16* thetac = (__bf16*)alloc((size_t)MROWS * KP * 2);
  float* cnt     = (float*)alloc((size_t)VDIM * 4);
  float* part_e  = (float*)alloc((size_t)EBLK * MROWS * 4);
  float* part_t  = (float*)alloc((size_t)EBLK * MROWS * 4);

  k_zero<<<(VDIM + 255) / 256, 256, 0, stream>>>(cnt);
  k_hist<<<(TTOK + 255) / 256, 256, 0, stream>>>(toks, cnt);
  k_fc1t<<<dim3(KPAD1 / 32, 4), 256, 0, stream>>>(fc1_w, fc1T);
  k_gemm1<<<dim3(16, NCH), 256, 0, stream>>>(bows, fc1T, partial);
  k_h1<<<(MROWS * HDIM + 255) / 256, 256, 0, stream>>>(partial, fc1_b, h1);
  k_mlp<<<MROWS, 256, 0, stream>>>(h1, fc2_w, fc2_b, mu_w, sig_w, mu_lin, sig_lin);
  k_bnstats<<<2 * KDIM, 256, 0, stream>>>(mu_lin, sig_lin, bn_mu_g, bn_mu_b, bn_sig_g, bn_sig_b, bnsc, bnsh);
  k_theta<<<(MROWS * KDIM + 255) / 256, 256, 0, stream>>>(mu_lin, sig_lin, eps, bnsc, bnsh, theta);
  k_tbar<<<KDIM, 256, 0, stream>>>(theta, tbar);
  k_center<<<(MROWS * KP + 255) / 256, 256, 0, stream>>>(theta, tbar, thetac);
  k_decode<<<EBLK, 512, 0, stream>>>(thetac, beta_w, bn_beta_g, bn_beta_b, cnt, part_e, part_t);
  k_final<<<MROWS / 32, 256, 0, stream>>>(part_e, part_t, (float*)d_out);
}

// Round 3
// 709.253 us; speedup vs baseline: 1.0641x; 1.0312x over previous
//
#include <hip/hip_runtime.h>
#include <hip/hip_bf16.h>

// NeLDA forward: loglik[b] = sum_v cnt_v * bnlin[b,v] - T * log(sum_v exp(bnlin[b,v]))
// bnlin[b,v] = g_v * (thetac_b . W_v) * rsqrt(var_v + eps) + bb_v   (all BN biases cancel)

using bf16x8 = __attribute__((ext_vector_type(8))) __bf16;
using f32x4  = __attribute__((ext_vector_type(4))) float;

#define MROWS 1024
#define VDIM  50000
#define VPAD  50048   // 782*64
#define HDIM  100
#define HP    112
#define KDIM  200
#define KP    224
#define TTOK  32768
#define KPAD1 50432
#define NCH   64
#define CHLEN 800
#define CPB   64      // decode cols per block
#define EBLK  782     // VPAD/CPB

__device__ __forceinline__ f32x4 mfma16(bf16x8 a, bf16x8 b, f32x4 c) {
  return __builtin_amdgcn_mfma_f32_16x16x32_bf16(a, b, c, 0, 0, 0);
}
__device__ __forceinline__ float softplus_f(float x) {
  return x > 20.f ? x : log1pf(__expf(x));
}

// ---------------- token histogram ----------------
__global__ void k_zero(float* __restrict__ cnt) {
  int id = blockIdx.x * 256 + threadIdx.x;
  if (id < VDIM) cnt[id] = 0.f;
}
__global__ void k_hist(const int* __restrict__ tok, float* __restrict__ cnt) {
  int id = blockIdx.x * 256 + threadIdx.x;
  if (id < TTOK) atomicAdd(&cnt[tok[id]], 1.f);
}

// ---------------- fc1_w [50000][100] -> bf16 col-major [112][50432] (zero padded) ----------------
__global__ __launch_bounds__(256) void k_fc1t(const float* __restrict__ w, __bf16* __restrict__ out) {
  __shared__ float tile[32][33];
  int kt = blockIdx.x, ct = blockIdx.y;
  int t = threadIdx.x;
  #pragma unroll
  for (int i = 0; i < 4; ++i) {
    int idx = t + i * 256;
    int lr = idx >> 5, lc = idx & 31;
    int gk = kt * 32 + lr, gc = ct * 32 + lc;
    tile[lr][lc] = (gk < VDIM && gc < HDIM) ? w[(size_t)gk * HDIM + gc] : 0.f;
  }
  __syncthreads();
  #pragma unroll
  for (int i = 0; i < 4; ++i) {
    int idx = t + i * 256;
    int lc = idx >> 5, lr = idx & 31;
    int gc = ct * 32 + lc, gk = kt * 32 + lr;
    if (gc < HP) out[(size_t)gc * KPAD1 + gk] = (__bf16)tile[lr][lc];
  }
}

// ---------------- beta_w [200][50000] -> bf16 row-major Wt [50048][224] (zero padded) ----------------
__global__ __launch_bounds__(256) void k_wt(const float* __restrict__ w, __bf16* __restrict__ out) {
  __shared__ float tile[32][33];
  int vt = blockIdx.x, kt = blockIdx.y;
  int t = threadIdx.x;
  #pragma unroll
  for (int i = 0; i < 4; ++i) {
    int idx = t + i * 256;
    int lr = idx >> 5, lc = idx & 31;          // lr: k, lc: v (coalesced along v)
    int gk = kt * 32 + lr, gv = vt * 32 + lc;
    tile[lr][lc] = (gk < KDIM && gv < VDIM) ? w[(size_t)gk * VDIM + gv] : 0.f;
  }
  __syncthreads();
  #pragma unroll
  for (int i = 0; i < 4; ++i) {
    int idx = t + i * 256;
    int lk = idx & 31, lv = idx >> 5;          // lk fast -> contiguous along k
    int gv = vt * 32 + lv, gk = kt * 32 + lk;
    if (gv < VPAD) out[(size_t)gv * KP + gk] = (__bf16)tile[lk][lv];
  }
}

// ---------------- GEMM1 split-K: partial[ch][row][112] = bows-chunk @ fc1 ----------------
__global__ __launch_bounds__(256, 4) void k_gemm1(const float* __restrict__ bows,
    const __bf16* __restrict__ fc1T, float* __restrict__ partial) {
  const int wave = threadIdx.x >> 6, lane = threadIdx.x & 63;
  const int lrow = lane & 15, lgrp = lane >> 4;
  const int rowbase = blockIdx.x * 64 + wave * 16;
  const int row = rowbase + lrow;
  const int ch = blockIdx.y;
  const int k0 = ch * CHLEN;
  const int kend = min(k0 + CHLEN, VDIM);
  const int nsteps = (kend - k0 + 31) >> 5;
  f32x4 acc[7] = {};
  const float* ap = bows + (size_t)row * VDIM;
  for (int s = 0; s < nsteps; ++s) {
    const int kl = k0 + s * 32 + lgrp * 8;
    bf16x8 a;
    if (kl + 8 <= VDIM) {
      f32x4 x0 = *(const f32x4*)(ap + kl);
      f32x4 x1 = *(const f32x4*)(ap + kl + 4);
      #pragma unroll
      for (int j = 0; j < 4; ++j) { a[j] = (__bf16)x0[j]; a[j + 4] = (__bf16)x1[j]; }
    } else {
      #pragma unroll
      for (int j = 0; j < 8; ++j) a[j] = (__bf16)((kl + j < VDIM) ? ap[kl + j] : 0.f);
    }
    #pragma unroll
    for (int n = 0; n < 7; ++n) {
      bf16x8 b = *(const bf16x8*)(fc1T + (size_t)(n * 16 + lrow) * KPAD1 + kl);
      acc[n] = mfma16(a, b, acc[n]);
    }
  }
  float* pp = partial + (size_t)ch * MROWS * HP;
  #pragma unroll
  for (int n = 0; n < 7; ++n) {
    #pragma unroll
    for (int r = 0; r < 4; ++r) {
      int rr = rowbase + lgrp * 4 + r;
      pp[(size_t)rr * HP + n * 16 + lrow] = acc[n][r];
    }
  }
}

// ---------------- reduce split-K + bias + softplus -> h1 [1024][100] ----------------
__global__ void k_h1(const float* __restrict__ partial, const float* __restrict__ fc1_b,
                     float* __restrict__ h1) {
  int id = blockIdx.x * 256 + threadIdx.x;
  if (id >= MROWS * HDIM) return;
  int row = id / HDIM, h = id % HDIM;
  float s = fc1_b[h];
  #pragma unroll 4
  for (int c = 0; c < NCH; ++c) s += partial[((size_t)c * MROWS + row) * HP + h];
  h1[id] = softplus_f(s);
}

// ---------------- fused: h2 = softplus(h1@fc2+b2); mu_lin/sig_lin (bias-free, cancels in BN) ----------------
__global__ __launch_bounds__(256) void k_mlp(const float* __restrict__ h1,
    const float* __restrict__ fc2_w, const float* __restrict__ fc2_b,
    const float* __restrict__ mu_w, const float* __restrict__ sig_w,
    float* __restrict__ mu_lin, float* __restrict__ sig_lin) {
  __shared__ float h1r[HDIM], h2r[HDIM];
  int row = blockIdx.x, t = threadIdx.x;
  if (t < HDIM) h1r[t] = h1[(size_t)row * HDIM + t];
  __syncthreads();
  if (t < HDIM) {
    float s = fc2_b[t];
    #pragma unroll 4
    for (int k = 0; k < HDIM; ++k) s += h1r[k] * fc2_w[k * HDIM + t];
    h2r[t] = softplus_f(s);
  }
  __syncthreads();
  if (t < KDIM) {
    float sm = 0.f, ss = 0.f;
    #pragma unroll 4
    for (int k = 0; k < HDIM; ++k) {
      float h = h2r[k];
      sm += h * mu_w[k * KDIM + t];
      ss += h * sig_w[k * KDIM + t];
    }
    mu_lin[(size_t)row * KDIM + t] = sm;
    sig_lin[(size_t)row * KDIM + t] = ss;
  }
}

// ---------------- BN stats for mu/sig: scale/shift per column ----------------
__global__ __launch_bounds__(256) void k_bnstats(const float* __restrict__ mu_lin,
    const float* __restrict__ sig_lin, const float* __restrict__ bn_mu_g,
    const float* __restrict__ bn_mu_b, const float* __restrict__ bn_sig_g,
    const float* __restrict__ bn_sig_b, float* __restrict__ bnsc, float* __restrict__ bnsh) {
  int bid = blockIdx.x;
  int mat = bid / KDIM, col = bid % KDIM;
  const float* src = mat ? sig_lin : mu_lin;
  int t = threadIdx.x;
  float s = 0.f, q = 0.f;
  for (int b = t; b < MROWS; b += 256) {
    float v = src[(size_t)b * KDIM + col];
    s += v; q += v * v;
  }
  #pragma unroll
  for (int d = 1; d < 64; d <<= 1) { s += __shfl_xor(s, d, 64); q += __shfl_xor(q, d, 64); }
  __shared__ float ls[4], lq[4];
  if ((t & 63) == 0) { ls[t >> 6] = s; lq[t >> 6] = q; }
  __syncthreads();
  if (t == 0) {
    s = ls[0] + ls[1] + ls[2] + ls[3];
    q = lq[0] + lq[1] + lq[2] + lq[3];
    float mean = s * (1.f / MROWS);
    float var = q * (1.f / MROWS) - mean * mean;
    float g = mat ? bn_sig_g[col] : bn_mu_g[col];
    float bb = mat ? bn_sig_b[col] : bn_mu_b[col];
    float sc = g * rsqrtf(var + 1e-5f);
    bnsc[mat * KDIM + col] = sc;
    bnsh[mat * KDIM + col] = bb - sc * mean;
  }
}

// ---------------- theta = exp(bn_mu + exp(0.5*bn_sig)*eps) ----------------
__global__ void k_theta(const float* __restrict__ mu_lin, const float* __restrict__ sig_lin,
    const float* __restrict__ eps, const float* __restrict__ bnsc, const float* __restrict__ bnsh,
    float* __restrict__ theta) {
  int id = blockIdx.x * 256 + threadIdx.x;
  if (id >= MROWS * KDIM) return;
  int k = id % KDIM;
  float mz = mu_lin[id] * bnsc[k] + bnsh[k];
  float sz = sig_lin[id] * bnsc[KDIM + k] + bnsh[KDIM + k];
  theta[id] = __expf(mz + __expf(0.5f * sz) * eps[id]);
}

// ---------------- column means of theta ----------------
__global__ __launch_bounds__(256) void k_tbar(const float* __restrict__ theta, float* __restrict__ tbar) {
  int col = blockIdx.x, t = threadIdx.x;
  float s = 0.f;
  for (int b = t; b < MROWS; b += 256) s += theta[(size_t)b * KDIM + col];
  #pragma unroll
  for (int d = 1; d < 64; d <<= 1) s += __shfl_xor(s, d, 64);
  __shared__ float ls[4];
  if ((t & 63) == 0) ls[t >> 6] = s;
  __syncthreads();
  if (t == 0) tbar[col] = (ls[0] + ls[1] + ls[2] + ls[3]) * (1.f / MROWS);
}

// ---------------- centered theta -> bf16 [1024][224] (zero padded K) ----------------
__global__ void k_center(const float* __restrict__ theta, const float* __restrict__ tbar,
                         __bf16* __restrict__ thetac) {
  int id = blockIdx.x * 256 + threadIdx.x;
  if (id >= MROWS * KP) return;
  int b = id / KP, kp = id % KP;
  thetac[id] = (kp < KDIM) ? (__bf16)(theta[(size_t)b * KDIM + kp] - tbar[kp]) : (__bf16)0.f;
}

// ---------------- fused decode: Dw = thetac@Wt^T (MFMA), batch var per col, exp-sum + cnt-weighted sum ----------------
// Block: 8 waves x 128 rows = all 1024 rows; 4 chunks x 16 cols = 64 cols/block.
// A-fragments read directly from global Wt (7 KB/chunk, shared by 8 waves via L1).
__global__ __launch_bounds__(512, 2) void k_decode(
    const __bf16* __restrict__ thetac,          // [1024][224]
    const __bf16* __restrict__ Wt,              // [50048][224]
    const float* __restrict__ bn_g, const float* __restrict__ bn_b,
    const float* __restrict__ cnt,
    float* __restrict__ part_e, float* __restrict__ part_t) {
  __shared__ float red[8][16];
  __shared__ float s_s[16], s_bb[16], s_ct[16];
  const int tid = threadIdx.x;
  const int wave = tid >> 6, lane = tid & 63;
  const int lrow = lane & 15, lgrp = lane >> 4;
  float esum[8] = {0, 0, 0, 0, 0, 0, 0, 0};
  float tsum[8] = {0, 0, 0, 0, 0, 0, 0, 0};
  const __bf16* tp = thetac + (size_t)(wave * 128 + lrow) * KP + lgrp * 8;

  #pragma unroll 1
  for (int chunk = 0; chunk < 4; ++chunk) {
    const int cb = blockIdx.x * CPB + chunk * 16;
    const __bf16* wp = Wt + (size_t)(cb + lrow) * KP + lgrp * 8;
    f32x4 acc[8];
    #pragma unroll
    for (int nf = 0; nf < 8; ++nf) acc[nf] = (f32x4){0, 0, 0, 0};
    #pragma unroll
    for (int ks = 0; ks < 7; ++ks) {
      bf16x8 a = *(const bf16x8*)(wp + ks * 32);
      #pragma unroll
      for (int nf = 0; nf < 8; ++nf) {
        bf16x8 b = *(const bf16x8*)(tp + (size_t)nf * 16 * KP + ks * 32);
        acc[nf] = mfma16(a, b, acc[nf]);
      }
    }
    // per-column (m = lgrp*4+r) sum of Dw^2 over all 1024 rows
    #pragma unroll
    for (int r = 0; r < 4; ++r) {
      float v = 0.f;
      #pragma unroll
      for (int nf = 0; nf < 8; ++nf) { float d = acc[nf][r]; v += d * d; }
      #pragma unroll
      for (int d = 1; d <= 8; d <<= 1) v += __shfl_xor(v, d, 64);
      if (lrow == 0) red[wave][lgrp * 4 + r] = v;
    }
    __syncthreads();
    if (tid < 16) {
      float v = 0.f;
      #pragma unroll
      for (int w8 = 0; w8 < 8; ++w8) v += red[w8][tid];
      float var = v * (1.f / 1024.f);
      int col = cb + tid;
      bool valid = col < VDIM;
      float g = valid ? bn_g[col] : 0.f;
      float bb = valid ? bn_b[col] : -87.f;
      float ct = valid ? cnt[col] : 0.f;
      s_s[tid] = g * rsqrtf(var + 1e-5f);
      s_bb[tid] = bb;
      s_ct[tid] = ct;
    }
    __syncthreads();
    // epilogue: bnlin = s*Dw + bb; accumulate exp and cnt*bnlin per row
    #pragma unroll
    for (int r = 0; r < 4; ++r) {
      int col = lgrp * 4 + r;
      float s = s_s[col], bb = s_bb[col], ct = s_ct[col];
      #pragma unroll
      for (int nf = 0; nf < 8; ++nf) {
        float z = s * acc[nf][r] + bb;
        esum[nf] += __expf(z);
        tsum[nf] += ct * z;
      }
    }
    // next chunk's red-write happens after the barrier below (in its own iteration),
    // so no extra barrier needed here: the chunk+1 first __syncthreads orders it.
  }
  // reduce over the 4 lane-groups (cols) and write per-row partials
  #pragma unroll
  for (int nf = 0; nf < 8; ++nf) {
    float e = esum[nf], t = tsum[nf];
    e += __shfl_xor(e, 16, 64); e += __shfl_xor(e, 32, 64);
    t += __shfl_xor(t, 16, 64); t += __shfl_xor(t, 32, 64);
    if (lgrp == 0) {
      int row = wave * 128 + nf * 16 + lrow;
      part_e[(size_t)blockIdx.x * MROWS + row] = e;
      part_t[(size_t)blockIdx.x * MROWS + row] = t;
    }
  }
}

// ---------------- final: loglik[b] = tok[b] - T*log(esum[b]) ----------------
__global__ __launch_bounds__(256) void k_final(const float* __restrict__ part_e,
    const float* __restrict__ part_t, float* __restrict__ out) {
  __shared__ float se[8][32], st[8][32];
  int t = threadIdx.x;
  int rloc = t & 31, g = t >> 5;
  int row = blockIdx.x * 32 + rloc;
  float e = 0.f, s = 0.f;
  for (int blk = g; blk < EBLK; blk += 8) {
    e += part_e[(size_t)blk * MROWS + row];
    s += part_t[(size_t)blk * MROWS + row];
  }
  se[g][rloc] = e; st[g][rloc] = s;
  __syncthreads();
  if (t < 32) {
    float et = 0.f, tt = 0.f;
    #pragma unroll
    for (int i = 0; i < 8; ++i) { et += se[i][t]; tt += st[i][t]; }
    out[blockIdx.x * 32 + t] = tt - 32768.f * logf(et);
  }
}

extern "C" void kernel_launch(void* const* d_in, const int* in_sizes, int n_in,
                              void* d_out, int out_size, void* d_ws, size_t ws_size,
                              hipStream_t stream) {
  (void)in_sizes; (void)n_in; (void)out_size; (void)ws_size;
  const float* bows      = (const float*)d_in[0];
  const float* eps       = (const float*)d_in[1];
  const int*   toks      = (const int*)d_in[2];
  const float* fc1_w     = (const float*)d_in[3];
  const float* fc1_b     = (const float*)d_in[4];
  const float* fc2_w     = (const float*)d_in[5];
  const float* fc2_b     = (const float*)d_in[6];
  const float* mu_w      = (const float*)d_in[7];
  const float* bn_mu_g   = (const float*)d_in[9];
  const float* bn_mu_b   = (const float*)d_in[10];
  const float* sig_w     = (const float*)d_in[11];
  const float* bn_sig_g  = (const float*)d_in[13];
  const float* bn_sig_b  = (const float*)d_in[14];
  const float* beta_w    = (const float*)d_in[15];
  const float* bn_beta_g = (const float*)d_in[17];
  const float* bn_beta_b = (const float*)d_in[18];

  char* w = (char*)d_ws;
  auto alloc = [&](size_t b) { char* p = w; w += (b + 255) & ~(size_t)255; return p; };
  __bf16* fc1T   = (__bf16*)alloc((size_t)HP * KPAD1 * 2);
  __bf16* Wt     = (__bf16*)alloc((size_t)VPAD * KP * 2);
  float* partial = (float*)alloc((size_t)NCH * MROWS * HP * 4);
  float* h1      = (float*)alloc((size_t)MROWS * HDIM * 4);
  float* mu_lin  = (float*)alloc((size_t)MROWS * KDIM * 4);
  float* sig_lin = (float*)alloc((size_t)MROWS * KDIM * 4);
  float* bnsc    = (float*)alloc(2 * KDIM * 4);
  float* bnsh    = (float*)alloc(2 * KDIM * 4);
  float* theta   = (float*)alloc((size_t)MROWS * KDIM * 4);
  float* tbar    = (float*)alloc(KDIM * 4);
  __bf16* thetac = (__bf16*)alloc((size_t)MROWS * KP * 2);
  float* cnt     = (float*)alloc((size_t)VDIM * 4);
  float* part_e  = (float*)alloc((size_t)EBLK * MROWS * 4);
  float* part_t  = (float*)alloc((size_t)EBLK * MROWS * 4);

  k_zero<<<(VDIM + 255) / 256, 256, 0, stream>>>(cnt);
  k_hist<<<(TTOK + 255) / 256, 256, 0, stream>>>(toks, cnt);
  k_fc1t<<<dim3(KPAD1 / 32, 4), 256, 0, stream>>>(fc1_w, fc1T);
  k_wt<<<dim3(VPAD / 32, KP / 32), 256, 0, stream>>>(beta_w, Wt);
  k_gemm1<<<dim3(16, NCH), 256, 0, stream>>>(bows, fc1T, partial);
  k_h1<<<(MROWS * HDIM + 255) / 256, 256, 0, stream>>>(partial, fc1_b, h1);
  k_mlp<<<MROWS, 256, 0, stream>>>(h1, fc2_w, fc2_b, mu_w, sig_w, mu_lin, sig_lin);
  k_bnstats<<<2 * KDIM, 256, 0, stream>>>(mu_lin, sig_lin, bn_mu_g, bn_mu_b, bn_sig_g, bn_sig_b, bnsc, bnsh);
  k_theta<<<(MROWS * KDIM + 255) / 256, 256, 0, stream>>>(mu_lin, sig_lin, eps, bnsc, bnsh, theta);
  k_tbar<<<KDIM, 256, 0, stream>>>(theta, tbar);
  k_center<<<(MROWS * KP + 255) / 256, 256, 0, stream>>>(theta, tbar, thetac);
  k_decode<<<EBLK, 512, 0, stream>>>(thetac, Wt, bn_beta_g, bn_beta_b, cnt, part_e, part_t);
  k_final<<<MROWS / 32, 256, 0, stream>>>(part_e, part_t, (float*)d_out);
}